// Round 9
// baseline (734.990 us; speedup 1.0000x reference)
//
#include <hip/hip_runtime.h>
#include <hip/hip_fp16.h>

#define N_NODES 100000
#define N_EDGES 3200000
#define F_IN 128
#define F_OUT 32
#define N_GRAPHS 64

#define NP   8                      // node partitions (XCDs)
#define PSZ  (N_NODES / NP)         // 12500 nodes per partition
#define NBKT 64                     // (src-part, dst-part) buckets
#define NCH  256                    // sort chunks (writer blocks)
#define CHUNK (N_EDGES / NCH)       // 12500, exact
#define NREG (NBKT * NCH)           // 16384 single-writer regions
#define UNROLL 4

// DPP ctrl encodings (gfx9+)
#define DPP_QUAD_XOR1   0xB1   // quad_perm(1,0,3,2)
#define DPP_QUAD_XOR2   0x4E   // quad_perm(2,3,0,1)
#define DPP_HALF_MIRROR 0x141  // lane ^ 7 within 8
#define DPP_ROW_MIRROR  0x140  // lane -> 15-lane within 16

template <int CTRL>
__device__ __forceinline__ float dpp_add(float v) {
    return v + __int_as_float(__builtin_amdgcn_update_dpp(
        0, __float_as_int(v), CTRL, 0xF, 0xF, true));
}

// ---------------------------------------------------------------------------
// Transform: xl = x@W_l + b_l ; xr = x@W_r + b_r, stored as fp16 rows (64B).
// ---------------------------------------------------------------------------
__global__ __launch_bounds__(256) void gat_transform(
    const float* __restrict__ x,
    const float* __restrict__ Wl, const float* __restrict__ bl,
    const float* __restrict__ Wr, const float* __restrict__ br,
    __half* __restrict__ xl16, __half* __restrict__ xr16)
{
    __shared__ float2 sW[F_IN * F_OUT];
    for (int i = threadIdx.x; i < F_IN * F_OUT; i += 256)
        sW[i] = make_float2(Wl[i], Wr[i]);
    __syncthreads();

    const int f     = threadIdx.x & 31;
    const int node0 = blockIdx.x * 32 + (threadIdx.x >> 5) * 4;

    const float4* x0 = (const float4*)(x + (size_t)(node0 + 0) * F_IN);
    const float4* x1 = (const float4*)(x + (size_t)(node0 + 1) * F_IN);
    const float4* x2 = (const float4*)(x + (size_t)(node0 + 2) * F_IN);
    const float4* x3 = (const float4*)(x + (size_t)(node0 + 3) * F_IN);

    const float bl_f = bl[f], br_f = br[f];
    float a0 = bl_f, a1 = bl_f, a2 = bl_f, a3 = bl_f;
    float r0 = br_f, r1 = br_f, r2 = br_f, r3 = br_f;

#pragma unroll 4
    for (int k4 = 0; k4 < F_IN / 4; ++k4) {
        float4 v0 = x0[k4], v1 = x1[k4], v2 = x2[k4], v3 = x3[k4];
        float2 w0 = sW[(4 * k4 + 0) * 32 + f];
        float2 w1 = sW[(4 * k4 + 1) * 32 + f];
        float2 w2 = sW[(4 * k4 + 2) * 32 + f];
        float2 w3 = sW[(4 * k4 + 3) * 32 + f];
        a0 += v0.x * w0.x + v0.y * w1.x + v0.z * w2.x + v0.w * w3.x;
        r0 += v0.x * w0.y + v0.y * w1.y + v0.z * w2.y + v0.w * w3.y;
        a1 += v1.x * w0.x + v1.y * w1.x + v1.z * w2.x + v1.w * w3.x;
        r1 += v1.x * w0.y + v1.y * w1.y + v1.z * w2.y + v1.w * w3.y;
        a2 += v2.x * w0.x + v2.y * w1.x + v2.z * w2.x + v2.w * w3.x;
        r2 += v2.x * w0.y + v2.y * w1.y + v2.z * w2.y + v2.w * w3.y;
        a3 += v3.x * w0.x + v3.y * w1.x + v3.z * w2.x + v3.w * w3.x;
        r3 += v3.x * w0.y + v3.y * w1.y + v3.z * w2.y + v3.w * w3.y;
    }
    xl16[(size_t)(node0 + 0) * 32 + f] = __float2half_rn(a0);
    xl16[(size_t)(node0 + 1) * 32 + f] = __float2half_rn(a1);
    xl16[(size_t)(node0 + 2) * 32 + f] = __float2half_rn(a2);
    xl16[(size_t)(node0 + 3) * 32 + f] = __float2half_rn(a3);
    xr16[(size_t)(node0 + 0) * 32 + f] = __float2half_rn(r0);
    xr16[(size_t)(node0 + 1) * 32 + f] = __float2half_rn(r1);
    xr16[(size_t)(node0 + 2) * 32 + f] = __float2half_rn(r2);
    xr16[(size_t)(node0 + 3) * 32 + f] = __float2half_rn(r3);
}

// ---------------------------------------------------------------------------
// 64-bucket sort by (src/PSZ, dst/PSZ), single-writer (bucket,chunk) regions.
// ---------------------------------------------------------------------------
__global__ __launch_bounds__(256) void part_hist(const int* __restrict__ ei,
                                                 int* __restrict__ cnt)
{
    __shared__ int h[NBKT];
    if (threadIdx.x < NBKT) h[threadIdx.x] = 0;
    __syncthreads();
    const int c  = blockIdx.x;
    const int e0 = c * CHUNK;
    for (int i = threadIdx.x; i < CHUNK; i += 256) {
        const int src = __builtin_nontemporal_load(&ei[e0 + i]);
        const int dst = __builtin_nontemporal_load(&ei[N_EDGES + e0 + i]);
        atomicAdd(&h[src / PSZ + NP * (dst / PSZ)], 1);
    }
    __syncthreads();
    if (threadIdx.x < NBKT) cnt[threadIdx.x * NCH + c] = h[threadIdx.x];
}

__global__ __launch_bounds__(1024) void part_scan(const int* __restrict__ cnt,
                                                  int* __restrict__ base)
{
    __shared__ int s[1024];
    const int t = threadIdx.x;            // covers entries [t*16, t*16+16)
    int loc[16];
    int sum = 0;
#pragma unroll
    for (int r = 0; r < 16; ++r) { loc[r] = cnt[t * 16 + r]; sum += loc[r]; }
    s[t] = sum;
    __syncthreads();
    for (int off = 1; off < 1024; off <<= 1) {
        const int u = (t >= off) ? s[t - off] : 0;
        __syncthreads();
        s[t] += u;
        __syncthreads();
    }
    int run = s[t] - sum;
#pragma unroll
    for (int r = 0; r < 16; ++r) { base[t * 16 + r] = run; run += loc[r]; }
    if (t == 1023) base[NREG] = run;      // == N_EDGES
}

__global__ __launch_bounds__(256) void part_scatter(const int* __restrict__ ei,
                                                    const float* __restrict__ eattr,
                                                    const int* __restrict__ base,
                                                    int2* __restrict__ es2)
{
    __shared__ int cur[NBKT];
    const int c = blockIdx.x;
    if (threadIdx.x < NBKT) cur[threadIdx.x] = base[threadIdx.x * NCH + c];
    __syncthreads();
    const int e0 = c * CHUNK;
    for (int i = threadIdx.x; i < CHUNK; i += 256) {
        const int src = __builtin_nontemporal_load(&ei[e0 + i]);
        const int dst = __builtin_nontemporal_load(&ei[N_EDGES + e0 + i]);
        const float ea = __builtin_nontemporal_load(&eattr[e0 + i]);
        const int sp = src / PSZ, dp = dst / PSZ;
        const int srcl = src - sp * PSZ;       // < 12500 < 2^14
        const int dstl = dst - dp * PSZ;
        const int pos = atomicAdd(&cur[sp + NP * dp], 1);
        const long long raw = (long long)(unsigned)(srcl | (dstl << 14))
                            | ((long long)__float_as_int(ea) << 32);
        __builtin_nontemporal_store(raw, (long long*)&es2[pos]);
    }
}

// ---------------------------------------------------------------------------
// Edge pass, XCD-partitioned: block b handles bucket (b & 63); since
// bkt%8 == b%8 == XCD id (round-robin dispatch), each XCD gathers only its
// 0.8MB xl16 slice + 0.8MB xr16 slice -> L2-resident. 32-lane group per
// edge, 4-edge ILP, DPP reduce, fire-and-forget f32 atomics.
// ---------------------------------------------------------------------------
__global__ __launch_bounds__(256) void gat_edge_part(
    const int2* __restrict__ es2, const int* __restrict__ base,
    const float* __restrict__ We, const float* __restrict__ att,
    const __half* __restrict__ xl16, const __half* __restrict__ xr16,
    float* __restrict__ outacc, float* __restrict__ denom)
{
    const int b    = blockIdx.x;
    const int bkt  = b & (NBKT - 1);
    const int slot = b >> 6;               // 0..31
    const int srcb = (bkt & (NP - 1)) * PSZ;
    const int dstb = (bkt >> 3) * PSZ;

    const int beg = base[bkt * NCH + slot * 8];
    const int end = base[bkt * NCH + slot * 8 + 8];

    const int f = threadIdx.x & 31;
    const int g = threadIdx.x >> 5;        // 0..7
    const float attf = att[f];
    const float wef  = We[f];

    const long long* es8 = (const long long*)es2;

    for (int e0 = beg + g; e0 < end; e0 += 8 * UNROLL) {
        long long raw[UNROLL];
        bool val[UNROLL];
        float xlv[UNROLL], xrv[UNROLL];
        int   dst[UNROLL];

#pragma unroll
        for (int u = 0; u < UNROLL; ++u) {
            const int j = e0 + u * 8;
            val[u] = (j < end);
            raw[u] = __builtin_nontemporal_load(&es8[val[u] ? j : beg]);
        }
#pragma unroll
        for (int u = 0; u < UNROLL; ++u) {
            const int lo   = (int)raw[u];
            const int src  = srcb + (lo & 0x3FFF);
            dst[u]         = dstb + ((lo >> 14) & 0x3FFF);
            xlv[u] = __half2float(xl16[(size_t)src * 32 + f]);
            xrv[u] = __half2float(xr16[(size_t)dst[u] * 32 + f]);
        }
#pragma unroll
        for (int u = 0; u < UNROLL; ++u) {
            const float ea = __int_as_float((int)(raw[u] >> 32));
            float m = xlv[u] + xrv[u] + ea * wef;
            m = (m > 0.f) ? m : 0.2f * m;
            float t = m * attf;
            t = dpp_add<DPP_QUAD_XOR1>(t);
            t = dpp_add<DPP_QUAD_XOR2>(t);
            t = dpp_add<DPP_HALF_MIRROR>(t);
            t = dpp_add<DPP_ROW_MIRROR>(t);
            t += __shfl_xor(t, 16, 32);
            const float p = __expf(t);
            if (val[u]) {
                unsafeAtomicAdd(&outacc[(size_t)dst[u] * 32 + f], xlv[u] * p);
                if (f == 0) unsafeAtomicAdd(&denom[dst[u]], p);
            }
        }
    }
}

// ---------------------------------------------------------------------------
// Pool: normalize by denom, add bias, mean over each graph's node range.
// ---------------------------------------------------------------------------
__global__ __launch_bounds__(256) void gat_pool_div(
    const float* __restrict__ outacc, const float* __restrict__ denom,
    const float* __restrict__ bias, const int* __restrict__ batch,
    float* __restrict__ out)
{
    const int g = blockIdx.x;
    __shared__ int s_lo, s_hi;
    if (threadIdx.x == 0) {
        int lo = 0, hi = N_NODES;
        while (lo < hi) { int mid = (lo + hi) >> 1; if (batch[mid] < g) lo = mid + 1; else hi = mid; }
        s_lo = lo;
        lo = 0; hi = N_NODES;
        while (lo < hi) { int mid = (lo + hi) >> 1; if (batch[mid] < g + 1) lo = mid + 1; else hi = mid; }
        s_hi = lo;
    }
    __syncthreads();
    const int lo = s_lo, hi = s_hi;

    const int f   = threadIdx.x & 31;
    const int grp = threadIdx.x >> 5;

    float acc = 0.f;
    for (int n = lo + grp; n < hi; n += 8)
        acc += outacc[(size_t)n * 32 + f] / (denom[n] + 1e-16f);

    __shared__ float s_acc[8][32];
    s_acc[grp][f] = acc;
    __syncthreads();

    if (threadIdx.x < 32) {
        float sum = 0.f;
#pragma unroll
        for (int i = 0; i < 8; ++i) sum += s_acc[i][f];
        const int cnt = hi - lo;
        out[g * 32 + f] = (cnt > 0) ? (sum / (float)cnt + bias[f]) : 0.f;
    }
}

// ---------------------------------------------------------------------------
extern "C" void kernel_launch(void* const* d_in, const int* in_sizes, int n_in,
                              void* d_out, int out_size, void* d_ws, size_t ws_size,
                              hipStream_t stream)
{
    const float* x     = (const float*)d_in[0];
    const float* eattr = (const float*)d_in[1];
    const float* Wl    = (const float*)d_in[2];
    const float* bl    = (const float*)d_in[3];
    const float* Wr    = (const float*)d_in[4];
    const float* br    = (const float*)d_in[5];
    const float* We    = (const float*)d_in[6];
    const float* att   = (const float*)d_in[7];
    const float* bias  = (const float*)d_in[8];
    const int*   ei    = (const int*)d_in[9];
    const int*   batch = (const int*)d_in[10];
    float* out = (float*)d_out;

    const size_t NF = (size_t)N_NODES * 32;   // 3.2M elements

    __half* xl16   = (__half*)d_ws;                       // 6.4 MB
    __half* xr16   = xl16 + NF;                           // 6.4 MB
    float*  outacc = (float*)(xr16 + NF);                 // 12.8 MB
    float*  denom  = outacc + NF;                         // 0.4 MB
    int2*   es2    = (int2*)(denom + N_NODES);            // 25.6 MB
    int*    cnt    = (int*)(es2 + N_EDGES);               // 64 KB
    int*    base   = cnt + NREG;                          // 64 KB + 4

    hipMemsetAsync(outacc, 0, (NF + N_NODES) * sizeof(float), stream);

    gat_transform<<<N_NODES / 32, 256, 0, stream>>>(x, Wl, bl, Wr, br, xl16, xr16);
    part_hist<<<NCH, 256, 0, stream>>>(ei, cnt);
    part_scan<<<1, 1024, 0, stream>>>(cnt, base);
    part_scatter<<<NCH, 256, 0, stream>>>(ei, eattr, base, es2);
    gat_edge_part<<<2048, 256, 0, stream>>>(es2, base, We, att, xl16, xr16, outacc, denom);
    gat_pool_div<<<N_GRAPHS, 256, 0, stream>>>(outacc, denom, bias, batch, out);
}